// Round 5
// baseline (1418.786 us; speedup 1.0000x reference)
//
#include <hip/hip_runtime.h>
#include <hip/hip_bf16.h>
#include <math.h>

#define VAR_N 4
#define LEVELS 17
#define NCELLS 56
#define PRED_N 12
#define TSTEPS 4096
#define DT 0.1f
#define RPB 16
#define LOG2E 1.44269504088896340736f

static __device__ __forceinline__ float rl(float x, int lane) {
    return __int_as_float(__builtin_amdgcn_readlane(__float_as_int(x), lane));
}
static __device__ __forceinline__ float rcpf(float x) {
    return __builtin_amdgcn_rcpf(x);
}

// ---------------------------------------------------------------------------
// Generic 5-layer MLP, row-wise. ReLU after layers 1-4; optional ReLU on 5.
// Parallelized over (row, out-col) pairs: RPB*dout work items per layer so
// small-dout layers (17) still use the whole block. float4 LDS reads.
// ---------------------------------------------------------------------------
template <int S>
__global__ void mlp5_kernel(const float* __restrict__ in, float* __restrict__ out,
                            const float* __restrict__ w1, const float* __restrict__ b1,
                            const float* __restrict__ w2, const float* __restrict__ b2,
                            const float* __restrict__ w3, const float* __restrict__ b3,
                            const float* __restrict__ w4, const float* __restrict__ b4,
                            const float* __restrict__ w5, const float* __restrict__ b5,
                            int nrows, int d0, int d1, int d2, int d3, int d4, int d5,
                            int relu_last) {
    extern __shared__ float lds[];
    float* bufA = lds;
    float* bufB = lds + RPB * S;
    const int r0 = blockIdx.x * RPB;
    const int tid = threadIdx.x;
    const int bt = blockDim.x;

    for (int idx = tid; idx < RPB * d0; idx += bt) {
        int r = idx / d0, c = idx - r * d0;
        int gr = r0 + r;
        bufA[r * S + c] = (gr < nrows) ? in[(size_t)gr * d0 + c] : 0.f;
    }
    __syncthreads();

    const float* Ws[5] = {w1, w2, w3, w4, w5};
    const float* Bs[5] = {b1, b2, b3, b4, b5};
    int dins[5] = {d0, d1, d2, d3, d4};
    int douts[5] = {d1, d2, d3, d4, d5};

    for (int L = 0; L < 5; ++L) {
        const float* __restrict__ W = Ws[L];
        const float* __restrict__ B = Bs[L];
        const int din = dins[L], dout = douts[L];
        const bool act = (L < 4) || (relu_last != 0);
        for (int idx = tid; idx < RPB * dout; idx += bt) {
            int r = idx / dout, j = idx - r * dout;
            float acc = B[j];
            const float* __restrict__ arow = bufA + r * S;
            int k = 0;
            for (; k + 4 <= din; k += 4) {
                const float4 hx = *(const float4*)(arow + k);
                acc = fmaf(hx.x, W[(size_t)(k + 0) * dout + j],
                       fmaf(hx.y, W[(size_t)(k + 1) * dout + j],
                        fmaf(hx.z, W[(size_t)(k + 2) * dout + j],
                         fmaf(hx.w, W[(size_t)(k + 3) * dout + j], acc))));
            }
            for (; k < din; ++k)
                acc = fmaf(arow[k], W[(size_t)k * dout + j], acc);
            if (act) acc = fmaxf(acc, 0.f);
            bufB[r * S + j] = acc;
        }
        __syncthreads();
        float* t = bufA; bufA = bufB; bufB = t;
    }

    for (int idx = tid; idx < RPB * d5; idx += bt) {
        int r = idx / d5, c = idx - r * d5;
        int gr = r0 + r;
        if (gr < nrows) out[(size_t)gr * d5 + c] = bufA[r * S + c];
    }
}

// ---------------------------------------------------------------------------
// TRANSPOSED + LOG2E-scaled g:
//   g[v][j][t] = LOG2E * (ltc_b[v][j] + sum_l u[v][t][l] * wx[v][l][j])
// ---------------------------------------------------------------------------
__global__ void gprep_kernel(const float* __restrict__ pre, const float* __restrict__ wx,
                             const float* __restrict__ b, float* __restrict__ g) {
    int idx = blockIdx.x * blockDim.x + threadIdx.x;
    if (idx >= VAR_N * NCELLS * TSTEPS) return;
    int t = idx % TSTEPS;
    int rem = idx / TSTEPS;
    int j = rem % NCELLS;
    int v = rem / NCELLS;
    const float* u = pre + (size_t)(v * 1024 + (t >> 2)) * 68 + (t & 3) * LEVELS;
    float acc = b[v * NCELLS + j];
#pragma unroll
    for (int l = 0; l < LEVELS; ++l)
        acc = fmaf(u[l], wx[(v * LEVELS + l) * NCELLS + j], acc);
    g[idx] = acc * LOG2E;
}

// ---------------------------------------------------------------------------
// Sequential LTC scan: 1 wave per var, 1 wave per EU.
// Per step: 1 ds_write + 14 back-to-back ds_read_b128 (schedule pinned via
// sched_group_barrier so the RA cannot re-chunk the reads), then 28 pk-fma.
// Update single-rcp: h' = (h(1+e)+alpha) / (cden(1+e)+dt), e = 2^(-z2).
// ---------------------------------------------------------------------------
__global__ void __launch_bounds__(64, 1) scan_kernel(
    const float* __restrict__ g, const float* __restrict__ wh,
    const float* __restrict__ a, const float* __restrict__ tau,
    const float* __restrict__ wx, const float* __restrict__ wout,
    const float* __restrict__ bout, const float* __restrict__ b,
    float* __restrict__ H, float* __restrict__ vs_t) {
    typedef float v2 __attribute__((ext_vector_type(2)));
    const int v = blockIdx.x;
    const int lane = threadIdx.x;
    const bool active = lane < NCELLS;
    const int j = active ? lane : (NCELLS - 1);
    __shared__ __align__(16) float hbuf[64];

    // lane j holds column j of wh (scaled by LOG2E), as 28 packed pairs over k
    v2 whp[28];
#pragma unroll
    for (int q = 0; q < 28; ++q) {
        float w0 = active ? wh[((size_t)v * NCELLS + 2 * q + 0) * NCELLS + lane] * LOG2E : 0.f;
        float w1 = active ? wh[((size_t)v * NCELLS + 2 * q + 1) * NCELLS + lane] * LOG2E : 0.f;
        v2 t; t.x = w0; t.y = w1;
        whp[q] = t;
    }
    const float alpha = active ? DT * a[v * NCELLS + lane] : 0.f;
    const float cden = active ? 1.f + DT / (tau[v * NCELLS + lane] + 0.5f) : 1.f;

    const float4* __restrict__ gv4 = (const float4*)(g + ((size_t)v * NCELLS + j) * TSTEPS);
    float* __restrict__ hp = H + (size_t)v * TSTEPS * NCELLS + lane;

    auto cell = [&](float h, float gcur) -> float {
        hbuf[lane] = h;   // ds_write; same-wave DS pipe ordering, no barrier
        const float4* h4 = (const float4*)hbuf;
        float4 hv[14];
#pragma unroll
        for (int q = 0; q < 14; ++q) hv[q] = h4[q];   // 14 ds_read_b128, broadcast
        v2 a0 = {0.f, 0.f}, a1 = {0.f, 0.f}, a2 = {0.f, 0.f}, a3 = {0.f, 0.f};
#pragma unroll
        for (int q = 0; q < 7; ++q) {
            float4 hq0 = hv[2 * q];
            float4 hq1 = hv[2 * q + 1];
            v2 p0; p0.x = hq0.x; p0.y = hq0.y;
            v2 p1; p1.x = hq0.z; p1.y = hq0.w;
            v2 p2; p2.x = hq1.x; p2.y = hq1.y;
            v2 p3; p3.x = hq1.z; p3.y = hq1.w;
            a0 = __builtin_elementwise_fma(p0, whp[4 * q + 0], a0);
            a1 = __builtin_elementwise_fma(p1, whp[4 * q + 1], a1);
            a2 = __builtin_elementwise_fma(p2, whp[4 * q + 2], a2);
            a3 = __builtin_elementwise_fma(p3, whp[4 * q + 3], a3);
        }
        v2 s = (a0 + a1) + (a2 + a3);
        float z2 = (gcur + s.x) + s.y;                // log2 domain
        float zc = fmaxf(z2, -80.f);                  // keep e finite
        float e = __builtin_amdgcn_exp2f(-zc);
        float t1 = 1.f + e;
        float num = fmaf(h, t1, alpha);
        float den = fmaf(cden, t1, DT);
        float hn = num * rcpf(den);
        // Pin the schedule: 1 ds_write, then ALL 14 ds_reads, then the VALU
        // pack. Keeps the reads contiguous so only one latency exposure.
        __builtin_amdgcn_sched_group_barrier(0x200, 1, 0);   // DS write
        __builtin_amdgcn_sched_group_barrier(0x100, 14, 0);  // DS reads
        __builtin_amdgcn_sched_group_barrier(0x002, 40, 0);  // VALU
        return hn;
    };

    float h = 0.f;
    float4 gq = gv4[0];
    for (int tq = 0; tq < TSTEPS / 4; ++tq) {
        float4 gn = gq;
        if (tq + 1 < TSTEPS / 4) gn = gv4[tq + 1];   // prefetch ~4 steps ahead
        h = cell(h, gq.x); if (active) hp[0 * NCELLS] = h;
        h = cell(h, gq.y); if (active) hp[1 * NCELLS] = h;
        h = cell(h, gq.z); if (active) hp[2 * NCELLS] = h;
        h = cell(h, gq.w); if (active) hp[3 * NCELLS] = h;
        hp += 4 * NCELLS;
        gq = gn;
    }

    // ---- autoregressive pred phase (12 steps; readlane is fine here) ----
    float wxcol[LEVELS];
#pragma unroll
    for (int l = 0; l < LEVELS; ++l)
        wxcol[l] = active ? wx[(v * LEVELS + l) * NCELLS + lane] * LOG2E : 0.f;
    float wtc[NCELLS];  // lane l (<17) holds wout[:, l]
#pragma unroll
    for (int jj = 0; jj < NCELLS; ++jj)
        wtc[jj] = (lane < LEVELS) ? wout[((size_t)v * NCELLS + jj) * LEVELS + lane] : 0.f;
    const float bj = active ? b[v * NCELLS + lane] * LOG2E : 0.f;
    const float boutl = (lane < LEVELS) ? bout[v * LEVELS + lane] : 0.f;

    float vv = boutl;
#pragma unroll
    for (int jj = 0; jj < NCELLS; ++jj) vv = fmaf(rl(h, jj), wtc[jj], vv);

    for (int i = 0; i < PRED_N; ++i) {
        float z2 = bj;
#pragma unroll
        for (int l = 0; l < LEVELS; ++l) z2 = fmaf(rl(vv, l), wxcol[l], z2);
#pragma unroll
        for (int k = 0; k < NCELLS; ++k) {
            float wk = (k & 1) ? whp[k >> 1].y : whp[k >> 1].x;
            z2 = fmaf(rl(h, k), wk, z2);
        }
        float zc = fmaxf(z2, -80.f);
        float e = __builtin_amdgcn_exp2f(-zc);
        float t1 = 1.f + e;
        h = fmaf(h, t1, alpha) * rcpf(fmaf(cden, t1, DT));
        vv = boutl;
#pragma unroll
        for (int jj = 0; jj < NCELLS; ++jj) vv = fmaf(rl(h, jj), wtc[jj], vv);
        if (lane < LEVELS)
            vs_t[((size_t)(TSTEPS + i) * VAR_N + v) * LEVELS + lane] = vv;
    }
}

// ---------------------------------------------------------------------------
// vs_t[t][v][l] = bout[v][l] + sum_j H[v][t][j] * wout[v][j][l]  (t < 4096)
// ---------------------------------------------------------------------------
__global__ void proj_kernel(const float* __restrict__ H, const float* __restrict__ wout,
                            const float* __restrict__ bout, float* __restrict__ vs_t) {
    int idx = blockIdx.x * blockDim.x + threadIdx.x;
    if (idx >= VAR_N * TSTEPS * LEVELS) return;
    int l = idx % LEVELS;
    int rem = idx / LEVELS;
    int t = rem % TSTEPS;
    int v = rem / TSTEPS;
    const float* hrow = H + ((size_t)v * TSTEPS + t) * NCELLS;
    float acc = bout[v * LEVELS + l];
#pragma unroll
    for (int jj = 0; jj < NCELLS; ++jj)
        acc = fmaf(hrow[jj], wout[(v * NCELLS + jj) * LEVELS + l], acc);
    vs_t[((size_t)t * VAR_N + v) * LEVELS + l] = acc;
}

// ---------------------------------------------------------------------------
extern "C" void kernel_launch(void* const* d_in, const int* in_sizes, int n_in,
                              void* d_out, int out_size, void* d_ws, size_t ws_size,
                              hipStream_t stream) {
    const float* x = (const float*)d_in[0];
    const float* pw[5] = {(const float*)d_in[1], (const float*)d_in[3], (const float*)d_in[5],
                          (const float*)d_in[7], (const float*)d_in[9]};
    const float* pb[5] = {(const float*)d_in[2], (const float*)d_in[4], (const float*)d_in[6],
                          (const float*)d_in[8], (const float*)d_in[10]};
    const float* c1w[5] = {(const float*)d_in[11], (const float*)d_in[13], (const float*)d_in[15],
                           (const float*)d_in[17], (const float*)d_in[19]};
    const float* c1b[5] = {(const float*)d_in[12], (const float*)d_in[14], (const float*)d_in[16],
                           (const float*)d_in[18], (const float*)d_in[20]};
    const float* c2w[5] = {(const float*)d_in[21], (const float*)d_in[23], (const float*)d_in[25],
                           (const float*)d_in[27], (const float*)d_in[29]};
    const float* c2b[5] = {(const float*)d_in[22], (const float*)d_in[24], (const float*)d_in[26],
                           (const float*)d_in[28], (const float*)d_in[30]};
    const float* ltc_wx = (const float*)d_in[31];
    const float* ltc_wh = (const float*)d_in[32];
    const float* ltc_b = (const float*)d_in[33];
    const float* ltc_a = (const float*)d_in[34];
    const float* ltc_tau = (const float*)d_in[35];
    const float* ltc_wout = (const float*)d_in[36];
    const float* ltc_bout = (const float*)d_in[37];

    float* ws = (float*)d_ws;
    float* pre = ws;                       // 4096*68      = 278528
    float* g = pre + 278528;               // 4*56*4096    = 917504  (transposed, LOG2E-scaled)
    float* H = g + 917504;                 // 4*4096*56    = 917504
    float* vs_t = H + 917504;              // 4108*4*17    = 279344
    float* y1 = vs_t + 279344;             // 4108*272     = 1117376
    float* out = (float*)d_out;            // 4108*68

    const int TROWS = TSTEPS + PRED_N;     // 4108

    // 1) preproc encoder: x(4096,68) -> pre(4096,68)
    {
        int nrows = TSTEPS;
        int blocks = (nrows + RPB - 1) / RPB;
        size_t shmem = 2 * RPB * 68 * sizeof(float);
        mlp5_kernel<68><<<blocks, 256, shmem, stream>>>(
            x, pre, pw[0], pb[0], pw[1], pb[1], pw[2], pb[2], pw[3], pb[3], pw[4], pb[4],
            nrows, 68, 68, 68, 68, 68, 68, 0);
    }
    // 2) g[v][j][t] = LOG2E * (b + u @ wx)
    {
        int n = VAR_N * NCELLS * TSTEPS;
        gprep_kernel<<<(n + 255) / 256, 256, 0, stream>>>(pre, ltc_wx, ltc_b, g);
    }
    // 3) sequential LTC scan (1 wave per var)
    scan_kernel<<<VAR_N, 64, 0, stream>>>(g, ltc_wh, ltc_a, ltc_tau, ltc_wx,
                                          ltc_wout, ltc_bout, ltc_b, H, vs_t);
    // 4) project observed-phase h to vs
    {
        int n = VAR_N * TSTEPS * LEVELS;
        proj_kernel<<<(n + 255) / 256, 256, 0, stream>>>(H, ltc_wout, ltc_bout, vs_t);
    }
    // 5) c1 encoder (+final relu): vs_t(16432,17) -> y1(16432,68) == (4108,272)
    {
        int nrows = TROWS * VAR_N;
        int blocks = (nrows + RPB - 1) / RPB;
        size_t shmem = 2 * RPB * 68 * sizeof(float);
        mlp5_kernel<68><<<blocks, 256, shmem, stream>>>(
            vs_t, y1, c1w[0], c1b[0], c1w[1], c1b[1], c1w[2], c1b[2], c1w[3], c1b[3],
            c1w[4], c1b[4], nrows, 17, 17, 17, 68, 68, 68, 1);
    }
    // 6) c2 encoder: y1(4108,272) -> out(4108,68)
    {
        int nrows = TROWS;
        int blocks = (nrows + RPB - 1) / RPB;
        size_t shmem = 2 * RPB * 272 * sizeof(float);
        mlp5_kernel<272><<<blocks, 256, shmem, stream>>>(
            y1, out, c2w[0], c2b[0], c2w[1], c2b[1], c2w[2], c2b[2], c2w[3], c2b[3],
            c2w[4], c2b[4], nrows, 272, 272, 272, 68, 68, 68, 0);
    }
}

// Round 6
// 1077.631 us; speedup vs baseline: 1.3166x; 1.3166x over previous
//
#include <hip/hip_runtime.h>
#include <hip/hip_bf16.h>
#include <math.h>

#define VAR_N 4
#define LEVELS 17
#define NCELLS 56
#define PRED_N 12
#define TSTEPS 4096
#define DT 0.1f
#define RPB 8
#define LOG2E 1.44269504088896340736f

static __device__ __forceinline__ float rl(float x, int lane) {
    return __int_as_float(__builtin_amdgcn_readlane(__float_as_int(x), lane));
}
static __device__ __forceinline__ float rcpf(float x) {
    return __builtin_amdgcn_rcpf(x);
}

// ---------------------------------------------------------------------------
// Generic 5-layer MLP, row-wise (R4 structure: thread-per-output-column with
// 8-row register accumulators, weight reused x8, float4 LDS reads).
// ---------------------------------------------------------------------------
template <int S>
__global__ void mlp5_kernel(const float* __restrict__ in, float* __restrict__ out,
                            const float* __restrict__ w1, const float* __restrict__ b1,
                            const float* __restrict__ w2, const float* __restrict__ b2,
                            const float* __restrict__ w3, const float* __restrict__ b3,
                            const float* __restrict__ w4, const float* __restrict__ b4,
                            const float* __restrict__ w5, const float* __restrict__ b5,
                            int nrows, int d0, int d1, int d2, int d3, int d4, int d5,
                            int relu_last) {
    extern __shared__ float lds[];
    float* bufA = lds;
    float* bufB = lds + RPB * S;
    const int r0 = blockIdx.x * RPB;
    const int tid = threadIdx.x;
    const int bt = blockDim.x;

    for (int idx = tid; idx < RPB * d0; idx += bt) {
        int r = idx / d0, c = idx - r * d0;
        int gr = r0 + r;
        bufA[r * S + c] = (gr < nrows) ? in[(size_t)gr * d0 + c] : 0.f;
    }
    __syncthreads();

    const float* Ws[5] = {w1, w2, w3, w4, w5};
    const float* Bs[5] = {b1, b2, b3, b4, b5};
    int dins[5] = {d0, d1, d2, d3, d4};
    int douts[5] = {d1, d2, d3, d4, d5};

    for (int L = 0; L < 5; ++L) {
        const float* __restrict__ W = Ws[L];
        const float* __restrict__ B = Bs[L];
        const int din = dins[L], dout = douts[L];
        const bool act = (L < 4) || (relu_last != 0);
        for (int j = tid; j < dout; j += bt) {
            float acc[RPB];
            float bj = B[j];
#pragma unroll
            for (int r = 0; r < RPB; ++r) acc[r] = bj;
            int k = 0;
            for (; k + 4 <= din; k += 4) {
                float w0v = W[(size_t)(k + 0) * dout + j];
                float w1v = W[(size_t)(k + 1) * dout + j];
                float w2v = W[(size_t)(k + 2) * dout + j];
                float w3v = W[(size_t)(k + 3) * dout + j];
#pragma unroll
                for (int r = 0; r < RPB; ++r) {
                    const float4 hx = *(const float4*)(bufA + r * S + k);
                    acc[r] = fmaf(hx.x, w0v,
                              fmaf(hx.y, w1v,
                               fmaf(hx.z, w2v,
                                fmaf(hx.w, w3v, acc[r]))));
                }
            }
            for (; k < din; ++k) {
                float wv = W[(size_t)k * dout + j];
#pragma unroll
                for (int r = 0; r < RPB; ++r)
                    acc[r] = fmaf(bufA[r * S + k], wv, acc[r]);
            }
#pragma unroll
            for (int r = 0; r < RPB; ++r) {
                float vo = acc[r];
                if (act) vo = fmaxf(vo, 0.f);
                bufB[r * S + j] = vo;
            }
        }
        __syncthreads();
        float* t = bufA; bufA = bufB; bufB = t;
    }

    for (int idx = tid; idx < RPB * d5; idx += bt) {
        int r = idx / d5, c = idx - r * d5;
        int gr = r0 + r;
        if (gr < nrows) out[(size_t)gr * d5 + c] = bufA[r * S + c];
    }
}

// ---------------------------------------------------------------------------
// TRANSPOSED + LOG2E-scaled g:
//   g[v][j][t] = LOG2E * (ltc_b[v][j] + sum_l u[v][t][l] * wx[v][l][j])
// ---------------------------------------------------------------------------
__global__ void gprep_kernel(const float* __restrict__ pre, const float* __restrict__ wx,
                             const float* __restrict__ b, float* __restrict__ g) {
    int idx = blockIdx.x * blockDim.x + threadIdx.x;
    if (idx >= VAR_N * NCELLS * TSTEPS) return;
    int t = idx % TSTEPS;
    int rem = idx / TSTEPS;
    int j = rem % NCELLS;
    int v = rem / NCELLS;
    const float* u = pre + (size_t)(v * 1024 + (t >> 2)) * 68 + (t & 3) * LEVELS;
    float acc = b[v * NCELLS + j];
#pragma unroll
    for (int l = 0; l < LEVELS; ++l)
        acc = fmaf(u[l], wx[(v * LEVELS + l) * NCELLS + j], acc);
    g[idx] = acc * LOG2E;
}

// ---------------------------------------------------------------------------
// Sequential LTC scan: 1 wave per var, 1 wave per EU.
// Per step: 1 ds_write + 14 back-to-back ds_read_b128 (schedule pinned via
// sched_group_barrier), then 28 pk-fma. Single-rcp update:
//   h' = (h(1+e)+alpha) / (cden(1+e)+dt),  e = 2^(-z2)  (LOG2E pre-folded).
// ---------------------------------------------------------------------------
__global__ void __launch_bounds__(64, 1) scan_kernel(
    const float* __restrict__ g, const float* __restrict__ wh,
    const float* __restrict__ a, const float* __restrict__ tau,
    const float* __restrict__ wx, const float* __restrict__ wout,
    const float* __restrict__ bout, const float* __restrict__ b,
    float* __restrict__ H, float* __restrict__ vs_t) {
    typedef float v2 __attribute__((ext_vector_type(2)));
    const int v = blockIdx.x;
    const int lane = threadIdx.x;
    const bool active = lane < NCELLS;
    const int j = active ? lane : (NCELLS - 1);
    __shared__ __align__(16) float hbuf[64];

    // lane j holds column j of wh (scaled by LOG2E), as 28 packed pairs over k
    v2 whp[28];
#pragma unroll
    for (int q = 0; q < 28; ++q) {
        float w0 = active ? wh[((size_t)v * NCELLS + 2 * q + 0) * NCELLS + lane] * LOG2E : 0.f;
        float w1 = active ? wh[((size_t)v * NCELLS + 2 * q + 1) * NCELLS + lane] * LOG2E : 0.f;
        v2 t; t.x = w0; t.y = w1;
        whp[q] = t;
    }
    const float alpha = active ? DT * a[v * NCELLS + lane] : 0.f;
    const float cden = active ? 1.f + DT / (tau[v * NCELLS + lane] + 0.5f) : 1.f;

    const float4* __restrict__ gv4 = (const float4*)(g + ((size_t)v * NCELLS + j) * TSTEPS);
    float* __restrict__ hp = H + (size_t)v * TSTEPS * NCELLS + lane;

    auto cell = [&](float h, float gcur) -> float {
        hbuf[lane] = h;   // ds_write; same-wave DS pipe ordering, no barrier
        const float4* h4 = (const float4*)hbuf;
        float4 hv[14];
#pragma unroll
        for (int q = 0; q < 14; ++q) hv[q] = h4[q];   // 14 ds_read_b128, broadcast
        v2 a0 = {0.f, 0.f}, a1 = {0.f, 0.f}, a2 = {0.f, 0.f}, a3 = {0.f, 0.f};
#pragma unroll
        for (int q = 0; q < 7; ++q) {
            float4 hq0 = hv[2 * q];
            float4 hq1 = hv[2 * q + 1];
            v2 p0; p0.x = hq0.x; p0.y = hq0.y;
            v2 p1; p1.x = hq0.z; p1.y = hq0.w;
            v2 p2; p2.x = hq1.x; p2.y = hq1.y;
            v2 p3; p3.x = hq1.z; p3.y = hq1.w;
            a0 = __builtin_elementwise_fma(p0, whp[4 * q + 0], a0);
            a1 = __builtin_elementwise_fma(p1, whp[4 * q + 1], a1);
            a2 = __builtin_elementwise_fma(p2, whp[4 * q + 2], a2);
            a3 = __builtin_elementwise_fma(p3, whp[4 * q + 3], a3);
        }
        v2 s = (a0 + a1) + (a2 + a3);
        float z2 = (gcur + s.x) + s.y;                // log2 domain
        float zc = fmaxf(z2, -80.f);                  // keep e finite
        float e = __builtin_amdgcn_exp2f(-zc);
        float t1 = 1.f + e;
        float num = fmaf(h, t1, alpha);
        float den = fmaf(cden, t1, DT);
        float hn = num * rcpf(den);
        // Pin the schedule: 1 ds_write, then ALL 14 ds_reads, then the VALU
        // pack. Keeps the reads contiguous so only one latency exposure.
        __builtin_amdgcn_sched_group_barrier(0x200, 1, 0);   // DS write
        __builtin_amdgcn_sched_group_barrier(0x100, 14, 0);  // DS reads
        __builtin_amdgcn_sched_group_barrier(0x002, 40, 0);  // VALU
        return hn;
    };

    float h = 0.f;
    float4 gq = gv4[0];
    for (int tq = 0; tq < TSTEPS / 4; ++tq) {
        float4 gn = gq;
        if (tq + 1 < TSTEPS / 4) gn = gv4[tq + 1];   // prefetch ~4 steps ahead
        h = cell(h, gq.x); if (active) hp[0 * NCELLS] = h;
        h = cell(h, gq.y); if (active) hp[1 * NCELLS] = h;
        h = cell(h, gq.z); if (active) hp[2 * NCELLS] = h;
        h = cell(h, gq.w); if (active) hp[3 * NCELLS] = h;
        hp += 4 * NCELLS;
        gq = gn;
    }

    // ---- autoregressive pred phase (12 steps; readlane is fine here) ----
    float wxcol[LEVELS];
#pragma unroll
    for (int l = 0; l < LEVELS; ++l)
        wxcol[l] = active ? wx[(v * LEVELS + l) * NCELLS + lane] * LOG2E : 0.f;
    float wtc[NCELLS];  // lane l (<17) holds wout[:, l]
#pragma unroll
    for (int jj = 0; jj < NCELLS; ++jj)
        wtc[jj] = (lane < LEVELS) ? wout[((size_t)v * NCELLS + jj) * LEVELS + lane] : 0.f;
    const float bj = active ? b[v * NCELLS + lane] * LOG2E : 0.f;
    const float boutl = (lane < LEVELS) ? bout[v * LEVELS + lane] : 0.f;

    float vv = boutl;
#pragma unroll
    for (int jj = 0; jj < NCELLS; ++jj) vv = fmaf(rl(h, jj), wtc[jj], vv);

    for (int i = 0; i < PRED_N; ++i) {
        float z2 = bj;
#pragma unroll
        for (int l = 0; l < LEVELS; ++l) z2 = fmaf(rl(vv, l), wxcol[l], z2);
#pragma unroll
        for (int k = 0; k < NCELLS; ++k) {
            float wk = (k & 1) ? whp[k >> 1].y : whp[k >> 1].x;
            z2 = fmaf(rl(h, k), wk, z2);
        }
        float zc = fmaxf(z2, -80.f);
        float e = __builtin_amdgcn_exp2f(-zc);
        float t1 = 1.f + e;
        h = fmaf(h, t1, alpha) * rcpf(fmaf(cden, t1, DT));
        vv = boutl;
#pragma unroll
        for (int jj = 0; jj < NCELLS; ++jj) vv = fmaf(rl(h, jj), wtc[jj], vv);
        if (lane < LEVELS)
            vs_t[((size_t)(TSTEPS + i) * VAR_N + v) * LEVELS + lane] = vv;
    }
}

// ---------------------------------------------------------------------------
// vs_t[t][v][l] = bout[v][l] + sum_j H[v][t][j] * wout[v][j][l]  (t < 4096)
// ---------------------------------------------------------------------------
__global__ void proj_kernel(const float* __restrict__ H, const float* __restrict__ wout,
                            const float* __restrict__ bout, float* __restrict__ vs_t) {
    int idx = blockIdx.x * blockDim.x + threadIdx.x;
    if (idx >= VAR_N * TSTEPS * LEVELS) return;
    int l = idx % LEVELS;
    int rem = idx / LEVELS;
    int t = rem % TSTEPS;
    int v = rem / TSTEPS;
    const float* hrow = H + ((size_t)v * TSTEPS + t) * NCELLS;
    float acc = bout[v * LEVELS + l];
#pragma unroll
    for (int jj = 0; jj < NCELLS; ++jj)
        acc = fmaf(hrow[jj], wout[(v * NCELLS + jj) * LEVELS + l], acc);
    vs_t[((size_t)t * VAR_N + v) * LEVELS + l] = acc;
}

// ---------------------------------------------------------------------------
extern "C" void kernel_launch(void* const* d_in, const int* in_sizes, int n_in,
                              void* d_out, int out_size, void* d_ws, size_t ws_size,
                              hipStream_t stream) {
    const float* x = (const float*)d_in[0];
    const float* pw[5] = {(const float*)d_in[1], (const float*)d_in[3], (const float*)d_in[5],
                          (const float*)d_in[7], (const float*)d_in[9]};
    const float* pb[5] = {(const float*)d_in[2], (const float*)d_in[4], (const float*)d_in[6],
                          (const float*)d_in[8], (const float*)d_in[10]};
    const float* c1w[5] = {(const float*)d_in[11], (const float*)d_in[13], (const float*)d_in[15],
                           (const float*)d_in[17], (const float*)d_in[19]};
    const float* c1b[5] = {(const float*)d_in[12], (const float*)d_in[14], (const float*)d_in[16],
                           (const float*)d_in[18], (const float*)d_in[20]};
    const float* c2w[5] = {(const float*)d_in[21], (const float*)d_in[23], (const float*)d_in[25],
                           (const float*)d_in[27], (const float*)d_in[29]};
    const float* c2b[5] = {(const float*)d_in[22], (const float*)d_in[24], (const float*)d_in[26],
                           (const float*)d_in[28], (const float*)d_in[30]};
    const float* ltc_wx = (const float*)d_in[31];
    const float* ltc_wh = (const float*)d_in[32];
    const float* ltc_b = (const float*)d_in[33];
    const float* ltc_a = (const float*)d_in[34];
    const float* ltc_tau = (const float*)d_in[35];
    const float* ltc_wout = (const float*)d_in[36];
    const float* ltc_bout = (const float*)d_in[37];

    float* ws = (float*)d_ws;
    float* pre = ws;                       // 4096*68      = 278528
    float* g = pre + 278528;               // 4*56*4096    = 917504  (transposed, LOG2E-scaled)
    float* H = g + 917504;                 // 4*4096*56    = 917504
    float* vs_t = H + 917504;              // 4108*4*17    = 279344
    float* y1 = vs_t + 279344;             // 4108*272     = 1117376
    float* out = (float*)d_out;            // 4108*68

    const int TROWS = TSTEPS + PRED_N;     // 4108

    // 1) preproc encoder: x(4096,68) -> pre(4096,68)
    {
        int nrows = TSTEPS;
        int blocks = (nrows + RPB - 1) / RPB;
        size_t shmem = 2 * RPB * 68 * sizeof(float);
        mlp5_kernel<68><<<blocks, 256, shmem, stream>>>(
            x, pre, pw[0], pb[0], pw[1], pb[1], pw[2], pb[2], pw[3], pb[3], pw[4], pb[4],
            nrows, 68, 68, 68, 68, 68, 68, 0);
    }
    // 2) g[v][j][t] = LOG2E * (b + u @ wx)
    {
        int n = VAR_N * NCELLS * TSTEPS;
        gprep_kernel<<<(n + 255) / 256, 256, 0, stream>>>(pre, ltc_wx, ltc_b, g);
    }
    // 3) sequential LTC scan (1 wave per var)
    scan_kernel<<<VAR_N, 64, 0, stream>>>(g, ltc_wh, ltc_a, ltc_tau, ltc_wx,
                                          ltc_wout, ltc_bout, ltc_b, H, vs_t);
    // 4) project observed-phase h to vs
    {
        int n = VAR_N * TSTEPS * LEVELS;
        proj_kernel<<<(n + 255) / 256, 256, 0, stream>>>(H, ltc_wout, ltc_bout, vs_t);
    }
    // 5) c1 encoder (+final relu): vs_t(16432,17) -> y1(16432,68) == (4108,272)
    {
        int nrows = TROWS * VAR_N;
        int blocks = (nrows + RPB - 1) / RPB;
        size_t shmem = 2 * RPB * 68 * sizeof(float);
        mlp5_kernel<68><<<blocks, 256, shmem, stream>>>(
            vs_t, y1, c1w[0], c1b[0], c1w[1], c1b[1], c1w[2], c1b[2], c1w[3], c1b[3],
            c1w[4], c1b[4], nrows, 17, 17, 17, 68, 68, 68, 1);
    }
    // 6) c2 encoder: y1(4108,272) -> out(4108,68)
    {
        int nrows = TROWS;
        int blocks = (nrows + RPB - 1) / RPB;
        size_t shmem = 2 * RPB * 272 * sizeof(float);
        mlp5_kernel<272><<<blocks, 256, shmem, stream>>>(
            y1, out, c2w[0], c2b[0], c2w[1], c2b[1], c2w[2], c2b[2], c2w[3], c2b[3],
            c2w[4], c2b[4], nrows, 272, 272, 272, 68, 68, 68, 0);
    }
}